// Round 3
// baseline (2143.352 us; speedup 1.0000x reference)
//
#include <hip/hip_runtime.h>

// Problem constants
#define NTOK 65536
#define DIMD 256
#define VOC  1024
#define NLEV 4

// GEMM tiling for the argmin kernel
#define TM 128   // tokens per block
#define TN 128   // codes per tile
#define DK 32    // d-chunk

// ---------------------------------------------------------------------------
// Bit-exact replication of numpy float32 semantics:
//   d2[n,v] = fl( fl( rnorm[n] - 2*dot(r_n,W_v) ) + wnorm[v] )
//   dot     = sequential fp32 FMA over d=0..255 (OpenBLAS sgemm, K<kc)
//   rnorm/wnorm = numpy pairwise sum (P256 = P128+P128; P128 = 8-accumulator
//                 unrolled loop + ((r0+r1)+(r2+r3))+((r4+r5)+(r6+r7)))
//   residual_{l+1} = fl(residual_l - W[idx])  elementwise
//   argmin: first minimum wins
//
// ws layout:
//   [0]        double loss_acc
//   [16]       float  wnorm[NLEV][VOC]   (16 KB)
//   [16400]    float  rnorm[NTOK]        (256 KB)
//   [278544]   int    idx[NLEV][NTOK]    (1 MB)
// residual lives in d_out[1:] (scratch until k_final_out rewrites it).
// ---------------------------------------------------------------------------

// numpy pairwise sum-of-squares of one 256-row; 16 lanes per row (j=0..15).
// Bit-exact value produced at j==0.
__device__ __forceinline__ float np_pairnorm_row(const float* row, int j)
{
#pragma clang fp contract(off)
    const int half = j >> 3;       // which 128-half
    const int jj   = j & 7;        // accumulator index
    const float* a = row + half * 128 + jj;
    float r = a[0] * a[0];
    #pragma unroll
    for (int i = 1; i < 16; ++i) {
        const float x  = a[8 * i];
        const float sq = x * x;    // rounded square (no fma contraction)
        r = r + sq;                // rounded add
    }
    // ((r0+r1)+(r2+r3))+((r4+r5)+(r6+r7)) then P0+P1 — fp32 add is
    // commutative, so the xor-tree is bit-identical to numpy's pairing.
    r = r + __shfl_xor(r, 1);
    r = r + __shfl_xor(r, 2);
    r = r + __shfl_xor(r, 4);
    r = r + __shfl_xor(r, 8);
    return r;
}

__global__ void k_pairnorm(const float* src, float* __restrict__ dst,
                           int nrows, double* loss_acc)
{
    if (loss_acc && blockIdx.x == 0 && threadIdx.x == 0) *loss_acc = 0.0;
    const int gtid  = blockIdx.x * blockDim.x + threadIdx.x;
    const int gwave = gtid >> 6;
    const int lane  = threadIdx.x & 63;
    const int nwave = (gridDim.x * blockDim.x) >> 6;
    const int sub   = lane >> 4;   // 4 rows per wave
    const int j     = lane & 15;
    for (int r4 = gwave; r4 * 4 < nrows; r4 += nwave) {
        const int row = r4 * 4 + sub;   // nrows is a multiple of 4
        const float v = np_pairnorm_row(src + (size_t)row * DIMD, j);
        if (j == 0) dst[row] = v;
    }
}

// Fused distance + argmin, numpy-fp32-bit-exact.
__global__ __launch_bounds__(256, 3)
void k_argmin(const float* rsrc, const float* __restrict__ embl,
              const float* __restrict__ rnorm, const float* __restrict__ wnorml,
              int* __restrict__ idxl)
{
    __shared__ float smem[DK * TM + DK * TN];   // 32 KB
    float* rbuf = smem;            // [DK][TM] d-major
    float* wbuf = smem + DK * TM;  // [DK][TN] d-major

    const int tid  = threadIdx.x;
    const int tx   = tid & 15;     // token group (8 tokens)
    const int ty   = tid >> 4;     // code group  (8 codes)
    const int tok0 = blockIdx.x * TM;

    float rn[8];
    #pragma unroll
    for (int i = 0; i < 8; ++i) rn[i] = rnorm[tok0 + tx * 8 + i];

    float m1[8]; int i1[8];
    #pragma unroll
    for (int i = 0; i < 8; ++i) { m1[i] = 3.0e38f; i1[i] = 0; }

    for (int ct = 0; ct < VOC / TN; ++ct) {
        float acc[8][8];
        #pragma unroll
        for (int i = 0; i < 8; ++i)
            #pragma unroll
            for (int j = 0; j < 8; ++j) acc[i][j] = 0.0f;

        for (int dc = 0; dc < DIMD / DK; ++dc) {
            __syncthreads();   // previous tile reads done before overwrite
            #pragma unroll
            for (int k4 = 0; k4 < 4; ++k4) {
                const int f  = tid + 256 * k4;   // 0..1023
                const int tt = f >> 3;           // 0..127
                const int d4 = f & 7;            // float4 slot in 32-d chunk
                const int dd = d4 * 4;
                {   // residual tile, transposed into LDS
                    const float4 rv = reinterpret_cast<const float4*>(
                        rsrc + (size_t)(tok0 + tt) * DIMD + dc * DK)[d4];
                    rbuf[(dd + 0) * TM + tt] = rv.x;
                    rbuf[(dd + 1) * TM + tt] = rv.y;
                    rbuf[(dd + 2) * TM + tt] = rv.z;
                    rbuf[(dd + 3) * TM + tt] = rv.w;
                }
                {   // codebook tile, transposed into LDS
                    const float4 wv = reinterpret_cast<const float4*>(
                        embl + (size_t)(ct * TN + tt) * DIMD + dc * DK)[d4];
                    wbuf[(dd + 0) * TN + tt] = wv.x;
                    wbuf[(dd + 1) * TN + tt] = wv.y;
                    wbuf[(dd + 2) * TN + tt] = wv.z;
                    wbuf[(dd + 3) * TN + tt] = wv.w;
                }
            }
            __syncthreads();

            // Sequential-k FMA chain per accumulator (d ascending) — matches
            // BLAS sgemm micro-kernel accumulation order bit-exactly.
            #pragma unroll 8
            for (int dd = 0; dd < DK; ++dd) {
                const float4 ra = *reinterpret_cast<const float4*>(&rbuf[dd * TM + tx * 8]);
                const float4 rb = *reinterpret_cast<const float4*>(&rbuf[dd * TM + tx * 8 + 4]);
                const float4 wa = *reinterpret_cast<const float4*>(&wbuf[dd * TN + ty * 8]);
                const float4 wb = *reinterpret_cast<const float4*>(&wbuf[dd * TN + ty * 8 + 4]);
                const float rv[8] = {ra.x, ra.y, ra.z, ra.w, rb.x, rb.y, rb.z, rb.w};
                const float wv[8] = {wa.x, wa.y, wa.z, wa.w, wb.x, wb.y, wb.z, wb.w};
                #pragma unroll
                for (int i = 0; i < 8; ++i)
                    #pragma unroll
                    for (int j = 0; j < 8; ++j)
                        acc[i][j] = fmaf(rv[i], wv[j], acc[i][j]);
            }
        }
        // finish tile: d2 = fl( fl(rnorm - 2*dot) + wnorm ); track first-min
        #pragma unroll
        for (int j = 0; j < 8; ++j) {
            const int c = ct * TN + ty * 8 + j;
            const float wn = wnorml[c];
            #pragma unroll
            for (int i = 0; i < 8; ++i) {
                const float t1 = rn[i] - 2.0f * acc[i][j];  // single rounding
                const float s  = t1 + wn;                   // second rounding
                if (s < m1[i]) { m1[i] = s; i1[i] = c; }
            }
        }
    }

    // merge argmin across the 16 ty-threads per token (reuse smem)
    __syncthreads();
    float* mm1 = smem;                      // [128][16]
    int*   mi1 = (int*)(smem + 128 * 16);
    #pragma unroll
    for (int i = 0; i < 8; ++i) {
        const int t = tx * 8 + i;
        mm1[t * 16 + ty] = m1[i];
        mi1[t * 16 + ty] = i1[i];
    }
    __syncthreads();
    if (tid < TM) {
        float b1 = 3.0e38f; int bi = 0x7fffffff;
        for (int k = 0; k < 16; ++k) {
            const float e1 = mm1[tid * 16 + k];
            const int   ei = mi1[tid * 16 + k];
            if (e1 < b1 || (e1 == b1 && ei < bi)) { b1 = e1; bi = ei; }
        }
        idxl[tok0 + tid] = bi;
    }
}

// Gather chosen code; loss += (q - r)^2; residual_{l+1} = fl(r - q).
// NOTE: rsrc and res may alias (in-place) — no __restrict__ on them.
__global__ void k_update(const float* rsrc, float* res, const float* embl,
                         const int* __restrict__ idxl, double* loss_acc, int write_res)
{
    const int gtid  = blockIdx.x * blockDim.x + threadIdx.x;
    const int gwave = gtid >> 6;
    const int lane  = threadIdx.x & 63;
    const int nwave = (gridDim.x * blockDim.x) >> 6;
    float lsum = 0.0f;
    for (int t = gwave; t < NTOK; t += nwave) {
        const int ci = idxl[t];
        const float4 q = reinterpret_cast<const float4*>(embl + (size_t)ci * DIMD)[lane];
        const float4 r = reinterpret_cast<const float4*>(rsrc + (size_t)t * DIMD)[lane];
        const float e0 = q.x - r.x, e1 = q.y - r.y, e2 = q.z - r.z, e3 = q.w - r.w;
        lsum += e0 * e0 + e1 * e1 + e2 * e2 + e3 * e3;
        if (write_res) {
            float4 nr;
            nr.x = r.x - q.x; nr.y = r.y - q.y; nr.z = r.z - q.z; nr.w = r.w - q.w;
            reinterpret_cast<float4*>(res + (size_t)t * DIMD)[lane] = nr;
        }
    }
    #pragma unroll
    for (int off = 32; off > 0; off >>= 1) lsum += __shfl_down(lsum, off);
    if (lane == 0) atomicAdd(loss_acc, (double)lsum);
}

// Rebuild code_sum with fp32 level-ordered adds; out = latent + (cs - latent).
__global__ void k_final_out(const float* __restrict__ latent, const float* __restrict__ emb,
                            const int* __restrict__ idx, float* outq)
{
    const int gtid  = blockIdx.x * blockDim.x + threadIdx.x;
    const int gwave = gtid >> 6;
    const int lane  = threadIdx.x & 63;
    const int nwave = (gridDim.x * blockDim.x) >> 6;
    for (int t = gwave; t < NTOK; t += nwave) {
        const float4 q0 = reinterpret_cast<const float4*>(
            emb + ((size_t)0 * VOC + idx[0 * NTOK + t]) * DIMD)[lane];
        const float4 q1 = reinterpret_cast<const float4*>(
            emb + ((size_t)1 * VOC + idx[1 * NTOK + t]) * DIMD)[lane];
        const float4 q2 = reinterpret_cast<const float4*>(
            emb + ((size_t)2 * VOC + idx[2 * NTOK + t]) * DIMD)[lane];
        const float4 q3 = reinterpret_cast<const float4*>(
            emb + ((size_t)3 * VOC + idx[3 * NTOK + t]) * DIMD)[lane];
        const float4 l4 = reinterpret_cast<const float4*>(latent + (size_t)t * DIMD)[lane];
        float4 o;
        { float c = q0.x; c = c + q1.x; c = c + q2.x; c = c + q3.x; o.x = l4.x + (c - l4.x); }
        { float c = q0.y; c = c + q1.y; c = c + q2.y; c = c + q3.y; o.y = l4.y + (c - l4.y); }
        { float c = q0.z; c = c + q1.z; c = c + q2.z; c = c + q3.z; o.z = l4.z + (c - l4.z); }
        { float c = q0.w; c = c + q1.w; c = c + q2.w; c = c + q3.w; o.w = l4.w + (c - l4.w); }
        reinterpret_cast<float4*>(outq + (size_t)t * DIMD)[lane] = o;
    }
}

__global__ void k_loss_final(const double* __restrict__ loss_acc, float* __restrict__ out0)
{
    *out0 = (float)(1.25 * (*loss_acc) / ((double)NTOK * (double)DIMD));
}

extern "C" void kernel_launch(void* const* d_in, const int* in_sizes, int n_in,
                              void* d_out, int out_size, void* d_ws, size_t ws_size,
                              hipStream_t stream)
{
    const float* latent = (const float*)d_in[0];
    const float* emb    = (const float*)d_in[1];
    float* out = (float*)d_out;
    float* res = out + 1;   // residual scratch; rewritten by k_final_out at the end

    char*   ws       = (char*)d_ws;
    double* loss_acc = (double*)ws;
    float*  wnorm    = (float*)(ws + 16);
    float*  rnorm    = (float*)(ws + 16 + NLEV * VOC * sizeof(float));
    int*    idx      = (int*)(ws + 16 + NLEV * VOC * sizeof(float) + NTOK * sizeof(float));

    // wnorm for all levels (+ loss reset)
    k_pairnorm<<<256, 256, 0, stream>>>(emb, wnorm, NLEV * VOC, loss_acc);

    for (int l = 0; l < NLEV; ++l) {
        const float* rsrc = l ? (const float*)res : latent;
        const float* W    = emb + (size_t)l * VOC * DIMD;
        int*         idxl = idx + l * NTOK;
        k_pairnorm<<<1024, 256, 0, stream>>>(rsrc, rnorm, NTOK, nullptr);
        k_argmin<<<NTOK / TM, 256, 0, stream>>>(rsrc, W, rnorm, wnorm + l * VOC, idxl);
        k_update<<<1024, 256, 0, stream>>>(rsrc, res, W, idxl, loss_acc, l < NLEV - 1);
    }
    k_final_out<<<1024, 256, 0, stream>>>(latent, emb, idx, res);
    k_loss_final<<<1, 1, 0, stream>>>(loss_acc, out);
}

// Round 4
// 1237.904 us; speedup vs baseline: 1.7314x; 1.7314x over previous
//
#include <hip/hip_runtime.h>

#define NTOK 65536
#define DIMD 256
#define VOC  1024
#define NLEV 4
#define TAU  0.03f   // screened top-2 gap below this -> exact numpy-fp32 rescan

typedef __attribute__((ext_vector_type(8))) short bf16x8;
typedef __attribute__((ext_vector_type(4))) float f32x4;

// ---------------------------------------------------------------------------
// ws layout:
//   [0]        double loss_acc ; [8] int ambig_count
//   [16]       float  wnorm[NLEV][VOC]     (16 KB)
//   [16400]    float  rnorm[NTOK]          (256 KB)
//   [278544]   int    idx[NLEV][NTOK]      (1 MB)
//   [1327120]  int    ambig_list[NTOK]     (256 KB)
//   [1589264]  uint4  wimg[NLEV*8*8*1024]  (4 MB)  pre-split, pre-swizzled W
// residual fp32 lives in d_out[1:] until k_final_out rewrites it.
// ---------------------------------------------------------------------------

__device__ __forceinline__ unsigned cvt_pk_bf16(float a, float b) {
    unsigned r;
    asm("v_cvt_pk_bf16_f32 %0, %1, %2" : "=v"(r) : "v"(a), "v"(b));
    return r;   // bits[15:0] = bf16(a), bits[31:16] = bf16(b)
}

// split 8 fp32 -> 8 bf16 hi (RNE) + 8 bf16 lo (RNE of x - hi)
__device__ __forceinline__ void split8(const float4 x0, const float4 x1,
                                       uint4& hi, uint4& lo) {
    hi.x = cvt_pk_bf16(x0.x, x0.y);
    hi.y = cvt_pk_bf16(x0.z, x0.w);
    hi.z = cvt_pk_bf16(x1.x, x1.y);
    hi.w = cvt_pk_bf16(x1.z, x1.w);
    const float l0 = x0.x - __uint_as_float(hi.x << 16);
    const float l1 = x0.y - __uint_as_float(hi.x & 0xffff0000u);
    const float l2 = x0.z - __uint_as_float(hi.y << 16);
    const float l3 = x0.w - __uint_as_float(hi.y & 0xffff0000u);
    const float l4 = x1.x - __uint_as_float(hi.z << 16);
    const float l5 = x1.y - __uint_as_float(hi.z & 0xffff0000u);
    const float l6 = x1.z - __uint_as_float(hi.w << 16);
    const float l7 = x1.w - __uint_as_float(hi.w & 0xffff0000u);
    lo.x = cvt_pk_bf16(l0, l1);
    lo.y = cvt_pk_bf16(l2, l3);
    lo.z = cvt_pk_bf16(l4, l5);
    lo.w = cvt_pk_bf16(l6, l7);
}

__device__ __forceinline__ void gl_lds16(const void* g, void* l) {
    __builtin_amdgcn_global_load_lds(
        (const __attribute__((address_space(1))) unsigned*)g,
        (__attribute__((address_space(3))) unsigned*)l, 16, 0, 0);
}

// --------- pre-split + pre-swizzle W into the LDS staging image -------------
// chunk = ((l*8 + ct)*8 + dc): 128 code-rows x 32 k; row layout in LDS:
// 8 granules of 16B: [hi k0..31 | lo k0..31], granule position g ^= (row&7).
__global__ void k_wsplit(const float* __restrict__ emb, uint4* __restrict__ wimg,
                         int* ambig_count)
{
    if (blockIdx.x == 0 && threadIdx.x == 0) *ambig_count = 0;
    const int chunk = blockIdx.x;          // 256 chunks
    const int l  = chunk >> 6;
    const int ct = (chunk >> 3) & 7;
    const int dc = chunk & 7;
    #pragma unroll
    for (int i = 0; i < 2; ++i) {
        const int s   = threadIdx.x + i * 256;   // 0..511
        const int row = s >> 2;
        const int ko  = s & 3;
        const int code = ct * 128 + row;
        const float* src = emb + ((size_t)(l * VOC + code)) * DIMD + dc * 32 + ko * 8;
        const float4 x0 = *reinterpret_cast<const float4*>(src);
        const float4 x1 = *reinterpret_cast<const float4*>(src + 4);
        uint4 hi, lo; split8(x0, x1, hi, lo);
        uint4* base = wimg + (size_t)chunk * 1024 + row * 8;
        base[(ko)     ^ (row & 7)] = hi;
        base[(4 + ko) ^ (row & 7)] = lo;
    }
}

// ------------------- numpy pairwise sum-of-squares --------------------------
__device__ __forceinline__ float np_pairnorm_row(const float* row, int j)
{
#pragma clang fp contract(off)
    const int half = j >> 3;
    const int jj   = j & 7;
    const float* a = row + half * 128 + jj;
    float r = a[0] * a[0];
    #pragma unroll
    for (int i = 1; i < 16; ++i) {
        const float x  = a[8 * i];
        const float sq = x * x;
        r = r + sq;
    }
    r = r + __shfl_xor(r, 1);
    r = r + __shfl_xor(r, 2);
    r = r + __shfl_xor(r, 4);
    r = r + __shfl_xor(r, 8);
    return r;
}

__global__ void k_pairnorm(const float* src, float* __restrict__ dst,
                           int nrows, double* loss_acc)
{
    if (loss_acc && blockIdx.x == 0 && threadIdx.x == 0) *loss_acc = 0.0;
    const int gtid  = blockIdx.x * blockDim.x + threadIdx.x;
    const int gwave = gtid >> 6;
    const int lane  = threadIdx.x & 63;
    const int nwave = (gridDim.x * blockDim.x) >> 6;
    const int sub   = lane >> 4;
    const int j     = lane & 15;
    for (int r4 = gwave; r4 * 4 < nrows; r4 += nwave) {
        const int row = r4 * 4 + sub;
        const float v = np_pairnorm_row(src + (size_t)row * DIMD, j);
        if (j == 0) dst[row] = v;
    }
}

// ------------------- MFMA screening (bf16-split, 3 passes) ------------------
// block: 128 tokens x (ct-loop over 8 x 128 codes); 4 waves 2x2.
__global__ __launch_bounds__(256, 2)
void k_screen(const float* rsrc, const uint4* __restrict__ wimg_l,
              const float* __restrict__ rnorm, const float* __restrict__ wnorml,
              int* __restrict__ idxl, int* __restrict__ ambig_list,
              int* __restrict__ ambig_count)
{
    __shared__ uint4 ldsA[1024];    // 16 KB: [128 tok-rows][8 granules] swizzled
    __shared__ uint4 ldsB[1024];    // 16 KB: [128 code-rows][8 granules] swizzled
    __shared__ float tM1[128][2];
    __shared__ float tM2[128][2];
    __shared__ int   tI1[128][2];

    const int tid  = threadIdx.x;
    const int lane = tid & 63;
    const int w    = tid >> 6;
    const int wm   = w >> 1;        // token half (0/1)
    const int wn   = w & 1;         // code half (0/1)
    const int lr   = lane & 15;     // frag row
    const int lg   = lane >> 4;     // k-octet group
    const int tok0 = blockIdx.x * 128;

    // preload rnorm for this lane's 16 tokens
    float rn[4][4];
    #pragma unroll
    for (int m = 0; m < 4; ++m)
        #pragma unroll
        for (int r = 0; r < 4; ++r)
            rn[m][r] = rnorm[tok0 + wm * 64 + m * 16 + lg * 4 + r];

    float m1[4][4], m2[4][4]; int i1[4][4];
    #pragma unroll
    for (int m = 0; m < 4; ++m)
        #pragma unroll
        for (int r = 0; r < 4; ++r) { m1[m][r] = 3.0e38f; m2[m][r] = 3.0e38f; i1[m][r] = 0; }

    for (int ct = 0; ct < 8; ++ct) {
        f32x4 acc[4][4];
        #pragma unroll
        for (int m = 0; m < 4; ++m)
            #pragma unroll
            for (int n = 0; n < 4; ++n) acc[m][n] = (f32x4)0.0f;

        for (int dc = 0; dc < 8; ++dc) {
            // ---- stage A (fp32 -> bf16 split, swizzled) ----
            #pragma unroll
            for (int i = 0; i < 2; ++i) {
                const int s   = tid + i * 256;
                const int row = s >> 2;
                const int ko  = s & 3;
                const float* src = rsrc + (size_t)(tok0 + row) * DIMD + dc * 32 + ko * 8;
                const float4 x0 = *reinterpret_cast<const float4*>(src);
                const float4 x1 = *reinterpret_cast<const float4*>(src + 4);
                uint4 hi, lo; split8(x0, x1, hi, lo);
                uint4* base = ldsA + row * 8;
                base[(ko)     ^ (row & 7)] = hi;
                base[(4 + ko) ^ (row & 7)] = lo;
            }
            // ---- stage B (pre-split image, linear global_load_lds) ----
            const uint4* bsrc = wimg_l + (size_t)(ct * 8 + dc) * 1024;
            #pragma unroll
            for (int i = 0; i < 4; ++i) {
                const int f = tid + i * 256;
                gl_lds16(bsrc + f, ldsB + f);
            }
            __syncthreads();

            // ---- one 16x16x32 k-step, 3 split passes ----
            bf16x8 ahi[4], alo[4];
            #pragma unroll
            for (int m = 0; m < 4; ++m) {
                const int row = wm * 64 + m * 16 + lr;
                ahi[m] = *reinterpret_cast<const bf16x8*>(&ldsA[row * 8 + ((lg)     ^ (row & 7))]);
                alo[m] = *reinterpret_cast<const bf16x8*>(&ldsA[row * 8 + ((4 + lg) ^ (row & 7))]);
            }
            #pragma unroll
            for (int n = 0; n < 4; ++n) {
                const int rowb = wn * 64 + n * 16 + lr;
                const bf16x8 bhi = *reinterpret_cast<const bf16x8*>(&ldsB[rowb * 8 + ((lg)     ^ (rowb & 7))]);
                const bf16x8 blo = *reinterpret_cast<const bf16x8*>(&ldsB[rowb * 8 + ((4 + lg) ^ (rowb & 7))]);
                #pragma unroll
                for (int m = 0; m < 4; ++m) {
                    acc[m][n] = __builtin_amdgcn_mfma_f32_16x16x32_bf16(ahi[m], bhi, acc[m][n], 0, 0, 0);
                    acc[m][n] = __builtin_amdgcn_mfma_f32_16x16x32_bf16(ahi[m], blo, acc[m][n], 0, 0, 0);
                    acc[m][n] = __builtin_amdgcn_mfma_f32_16x16x32_bf16(alo[m], bhi, acc[m][n], 0, 0, 0);
                }
            }
            __syncthreads();
        }
        // ---- per-ct top-2 update (lane-local) ----
        #pragma unroll
        for (int n = 0; n < 4; ++n) {
            const int c = ct * 128 + wn * 64 + n * 16 + lr;
            const float wnv = wnorml[c];
            #pragma unroll
            for (int m = 0; m < 4; ++m)
                #pragma unroll
                for (int r = 0; r < 4; ++r) {
                    const float s = fmaf(-2.0f, acc[m][n][r], rn[m][r]) + wnv;
                    if (s < m1[m][r]) { m2[m][r] = m1[m][r]; m1[m][r] = s; i1[m][r] = c; }
                    else if (s < m2[m][r]) { m2[m][r] = s; }
                }
        }
    }

    // ---- butterfly merge across the 16 col-lanes, then LDS cross-wave merge ----
    #pragma unroll
    for (int m = 0; m < 4; ++m)
        #pragma unroll
        for (int r = 0; r < 4; ++r) {
            float a1 = m1[m][r], a2 = m2[m][r]; int ai = i1[m][r];
            #pragma unroll
            for (int d = 1; d < 16; d <<= 1) {
                const float o1 = __shfl_xor(a1, d);
                const float o2 = __shfl_xor(a2, d);
                const int   oi = __shfl_xor(ai, d);
                if (o1 < a1 || (o1 == a1 && oi < ai)) { a2 = fminf(a1, o2); a1 = o1; ai = oi; }
                else { a2 = fminf(a2, fminf(o1, o2)); }
            }
            if (lr == 0) {
                const int t = wm * 64 + m * 16 + lg * 4 + r;
                tM1[t][wn] = a1; tM2[t][wn] = a2; tI1[t][wn] = ai;
            }
        }
    __syncthreads();
    if (tid < 128) {
        float a1 = tM1[tid][0], a2 = tM2[tid][0]; int ai = tI1[tid][0];
        const float o1 = tM1[tid][1], o2 = tM2[tid][1]; const int oi = tI1[tid][1];
        if (o1 < a1 || (o1 == a1 && oi < ai)) { a2 = fminf(a1, o2); a1 = o1; ai = oi; }
        else { a2 = fminf(a2, fminf(o1, o2)); }
        const int gt = tok0 + tid;
        idxl[gt] = ai;
        if (a2 - a1 < TAU) {
            const int p = atomicAdd(ambig_count, 1);
            ambig_list[p] = gt;
        }
    }
}

// ---------------- exact numpy-fp32 rescan for ambiguous tokens --------------
__global__ void k_rescue(const float* rsrc, const float* __restrict__ embl,
                         const float* __restrict__ rnorm, const float* __restrict__ wnorml,
                         const int* __restrict__ ambig_list, const int* __restrict__ ambig_count,
                         int* __restrict__ idxl)
{
    __shared__ float rbuf[DIMD];
    const int lane = threadIdx.x;   // blockDim.x == 64
    int cnt = *ambig_count; if (cnt > NTOK) cnt = NTOK;
    for (int k = blockIdx.x; k < cnt; k += gridDim.x) {
        const int t = ambig_list[k];
        reinterpret_cast<float4*>(rbuf)[lane] =
            reinterpret_cast<const float4*>(rsrc + (size_t)t * DIMD)[lane];
        __syncthreads();
        const float rnv = rnorm[t];
        float best = 3.0e38f; int besti = 0x7fffffff;
        for (int j = 0; j < 16; ++j) {
            const int c = j * 64 + lane;
            const float* wr = embl + (size_t)c * DIMD;
            float acc = 0.0f;
            for (int d = 0; d < DIMD; d += 4) {   // sequential fmaf, d ascending
                const float4 wv = *reinterpret_cast<const float4*>(wr + d);
                acc = fmaf(rbuf[d + 0], wv.x, acc);
                acc = fmaf(rbuf[d + 1], wv.y, acc);
                acc = fmaf(rbuf[d + 2], wv.z, acc);
                acc = fmaf(rbuf[d + 3], wv.w, acc);
            }
            const float s = fmaf(-2.0f, acc, rnv) + wnorml[c];  // == numpy two-rounding
            if (s < best || (s == best && c < besti)) { best = s; besti = c; }
        }
        #pragma unroll
        for (int off = 32; off > 0; off >>= 1) {
            const float ov = __shfl_down(best, off);
            const int   oi = __shfl_down(besti, off);
            if (ov < best || (ov == best && oi < besti)) { best = ov; besti = oi; }
        }
        if (lane == 0) idxl[t] = besti;
        __syncthreads();
    }
}

// ---- gather chosen code; loss += (q-r)^2; residual_{l+1} = fl(r - q) -------
__global__ void k_update(const float* rsrc, float* res, const float* embl,
                         const int* __restrict__ idxl, double* loss_acc,
                         int* ambig_count, int write_res)
{
    if (blockIdx.x == 0 && threadIdx.x == 0) *ambig_count = 0;
    const int gtid  = blockIdx.x * blockDim.x + threadIdx.x;
    const int gwave = gtid >> 6;
    const int lane  = threadIdx.x & 63;
    const int nwave = (gridDim.x * blockDim.x) >> 6;
    float lsum = 0.0f;
    for (int t = gwave; t < NTOK; t += nwave) {
        const int ci = idxl[t];
        const float4 q = reinterpret_cast<const float4*>(embl + (size_t)ci * DIMD)[lane];
        const float4 r = reinterpret_cast<const float4*>(rsrc + (size_t)t * DIMD)[lane];
        const float e0 = q.x - r.x, e1 = q.y - r.y, e2 = q.z - r.z, e3 = q.w - r.w;
        lsum += e0 * e0 + e1 * e1 + e2 * e2 + e3 * e3;
        if (write_res) {
            float4 nr;
            nr.x = r.x - q.x; nr.y = r.y - q.y; nr.z = r.z - q.z; nr.w = r.w - q.w;
            reinterpret_cast<float4*>(res + (size_t)t * DIMD)[lane] = nr;
        }
    }
    #pragma unroll
    for (int off = 32; off > 0; off >>= 1) lsum += __shfl_down(lsum, off);
    if (lane == 0) atomicAdd(loss_acc, (double)lsum);
}

__global__ void k_final_out(const float* __restrict__ latent, const float* __restrict__ emb,
                            const int* __restrict__ idx, float* outq)
{
    const int gtid  = blockIdx.x * blockDim.x + threadIdx.x;
    const int gwave = gtid >> 6;
    const int lane  = threadIdx.x & 63;
    const int nwave = (gridDim.x * blockDim.x) >> 6;
    for (int t = gwave; t < NTOK; t += nwave) {
        const float4 q0 = reinterpret_cast<const float4*>(
            emb + ((size_t)0 * VOC + idx[0 * NTOK + t]) * DIMD)[lane];
        const float4 q1 = reinterpret_cast<const float4*>(
            emb + ((size_t)1 * VOC + idx[1 * NTOK + t]) * DIMD)[lane];
        const float4 q2 = reinterpret_cast<const float4*>(
            emb + ((size_t)2 * VOC + idx[2 * NTOK + t]) * DIMD)[lane];
        const float4 q3 = reinterpret_cast<const float4*>(
            emb + ((size_t)3 * VOC + idx[3 * NTOK + t]) * DIMD)[lane];
        const float4 l4 = reinterpret_cast<const float4*>(latent + (size_t)t * DIMD)[lane];
        float4 o;
        { float c = q0.x; c = c + q1.x; c = c + q2.x; c = c + q3.x; o.x = l4.x + (c - l4.x); }
        { float c = q0.y; c = c + q1.y; c = c + q2.y; c = c + q3.y; o.y = l4.y + (c - l4.y); }
        { float c = q0.z; c = c + q1.z; c = c + q2.z; c = c + q3.z; o.z = l4.z + (c - l4.z); }
        { float c = q0.w; c = c + q1.w; c = c + q2.w; c = c + q3.w; o.w = l4.w + (c - l4.w); }
        reinterpret_cast<float4*>(outq + (size_t)t * DIMD)[lane] = o;
    }
}

__global__ void k_loss_final(const double* __restrict__ loss_acc, float* __restrict__ out0)
{
    *out0 = (float)(1.25 * (*loss_acc) / ((double)NTOK * (double)DIMD));
}

extern "C" void kernel_launch(void* const* d_in, const int* in_sizes, int n_in,
                              void* d_out, int out_size, void* d_ws, size_t ws_size,
                              hipStream_t stream)
{
    const float* latent = (const float*)d_in[0];
    const float* emb    = (const float*)d_in[1];
    float* out = (float*)d_out;
    float* res = out + 1;   // residual scratch; rewritten by k_final_out

    char*   ws        = (char*)d_ws;
    double* loss_acc  = (double*)ws;
    int*    ambig_cnt = (int*)(ws + 8);
    float*  wnorm     = (float*)(ws + 16);
    float*  rnorm     = (float*)(ws + 16 + NLEV * VOC * sizeof(float));
    int*    idx       = (int*)(ws + 16 + NLEV * VOC * sizeof(float) + NTOK * sizeof(float));
    int*    ambl      = idx + NLEV * NTOK;
    uint4*  wimg      = (uint4*)((char*)(ambl + NTOK));

    k_wsplit<<<256, 256, 0, stream>>>(emb, wimg, ambig_cnt);
    k_pairnorm<<<256, 256, 0, stream>>>(emb, wnorm, NLEV * VOC, loss_acc);

    for (int l = 0; l < NLEV; ++l) {
        const float* rsrc = l ? (const float*)res : latent;
        const float* W    = emb + (size_t)l * VOC * DIMD;
        int*         idxl = idx + l * NTOK;
        k_pairnorm<<<1024, 256, 0, stream>>>(rsrc, rnorm, NTOK, nullptr);
        k_screen<<<NTOK / 128, 256, 0, stream>>>(rsrc, wimg + (size_t)l * 65536,
                                                 rnorm, wnorm + l * VOC,
                                                 idxl, ambl, ambig_cnt);
        k_rescue<<<1024, 64, 0, stream>>>(rsrc, W, rnorm, wnorm + l * VOC,
                                          ambl, ambig_cnt, idxl);
        k_update<<<1024, 256, 0, stream>>>(rsrc, res, W, idxl, loss_acc,
                                           ambig_cnt, l < NLEV - 1);
    }
    k_final_out<<<1024, 256, 0, stream>>>(latent, emb, idx, res);
    k_loss_final<<<1, 1, 0, stream>>>(loss_acc, out);
}